// Round 5
// baseline (722.922 us; speedup 1.0000x reference)
//
#include <hip/hip_runtime.h>
#include <math.h>

#define N_VAR 8192
#define N_CHK 4096
#define DV 3
#define N_EDGE (N_VAR * DV)
#define BATCH 128
#define T_ITERS 30
#define ELLW 32

#define LOG2E 1.44269504088896340736f
#define LN2   0.69314718055994530942f
#define LN_EPS -16.118095651f   /* ln(1e-7) */

typedef float v4f __attribute__((ext_vector_type(4)));
typedef _Float16 h4 __attribute__((ext_vector_type(4)));

__device__ __forceinline__ float fast_exp(float x) {   // e^x
    return __builtin_amdgcn_exp2f(x * LOG2E);
}

// log|tanh(x/2)|, x pre-clipped to [-15,15]; u = |x|
__device__ __forceinline__ float log_tanh_half(float u) {
    float E = __builtin_amdgcn_exp2f(-u * LOG2E);          // e^-u
    float la_big = (__builtin_amdgcn_logf(1.0f - E) -
                    __builtin_amdgcn_logf(1.0f + E)) * LN2;
    float z = 0.5f * u;                                    // small-u Taylor
    float zz = z * z;
    float ts = z * (1.0f - zz * (0.33333333f - 0.13333333f * zz));
    float la_small = __builtin_amdgcn_logf(ts) * LN2;
    float la = (u < 0.25f) ? la_small : la_big;
    return fmaxf(la, LN_EPS);
}

// 2*atanh(e^L) for L <= 0, clipped like the reference
__device__ __forceinline__ float back_transform(float L) {
    float p = __builtin_amdgcn_exp2f(L * LOG2E);
    p = fminf(p, 1.0f - 1e-7f);
    return (__builtin_amdgcn_logf(1.0f + p) -
            __builtin_amdgcn_logf(1.0f - p)) * LN2;
}

// ---------------- ELL build (once per launch) ------------------------------

__global__ void k_ell_scatter(const int* __restrict__ edge_chk,
                              int* __restrict__ deg_arr, int* __restrict__ ell) {
    int e = blockIdx.x * blockDim.x + threadIdx.x;
    if (e < N_EDGE) {
        int c = edge_chk[e];
        int pos = atomicAdd(&deg_arr[c], 1);
        if (pos < ELLW) ell[c * ELLW + pos] = e;
    }
}

// exclusive prefix over 4096 degs -> ptr (compact V2C slot offsets)
__global__ __launch_bounds__(1024) void k_scan(const int* __restrict__ counts,
                                               int* __restrict__ ptr) {
    __shared__ int bufA[1024];
    __shared__ int bufB[1024];
    int t = threadIdx.x;
    int c0 = counts[4 * t + 0];
    int c1 = counts[4 * t + 1];
    int c2 = counts[4 * t + 2];
    int c3 = counts[4 * t + 3];
    int s = c0 + c1 + c2 + c3;
    bufA[t] = s;
    __syncthreads();
    int* src = bufA;
    int* dst = bufB;
    for (int off = 1; off < 1024; off *= 2) {
        int v = src[t];
        if (t >= off) v += src[t - off];
        dst[t] = v;
        __syncthreads();
        int* tmp = src; src = dst; dst = tmp;
    }
    int incl = src[t];
    int excl = incl - s;
    ptr[4 * t + 0] = excl;
    ptr[4 * t + 1] = excl + c0;
    ptr[4 * t + 2] = excl + c0 + c1;
    ptr[4 * t + 3] = excl + c0 + c1 + c2;
    if (t == 1023) ptr[N_CHK] = incl;
}

// ---------------- Fused iteration: one dispatch = one BP iteration ---------
// Team (128 threads) per check. Per edge e=3v+k of the check:
//   tot[v] = chn[v] + C2V_prev[3v..3v+2]   (gathered; also = out[iter-1][v])
//   V2C[e] = g*(tot - C2V_prev[e]) + (1-g)*V2C_old[e]   (V2C private to team)
//   tanh-domain check math -> C2V_next[e]
// Kernel boundary is the only sync; C2V double-buffered in fp16.

__global__ __launch_bounds__(256) void k_fused(
        const float* __restrict__ chn,
        const float* __restrict__ gamma_logit,
        const _Float16* __restrict__ c2v_prev,
        _Float16* __restrict__ c2v_next,
        _Float16* __restrict__ v2c,
        const int* __restrict__ deg_arr,
        const int* __restrict__ ell,
        const int* __restrict__ ptr,
        float* __restrict__ out, int iter) {
    int c = blockIdx.x * 2 + (threadIdx.x >> 7);
    int b = threadIdx.x & 127;
    int deg = deg_arr[c];
    if (deg > ELLW) deg = ELLW;
    int base = ptr[c];
    float g = 1.0f / (1.0f + fast_exp(-gamma_logit[0]));
    float om = 1.0f - g;
    float* out_t = out + (size_t)(iter - 1) * (N_VAR * BATCH);

    float la[ELLW];
    float sum_log = 0.0f;
    unsigned mask = 0u;

#define P1(J) { \
    int e = ell[c * ELLW + (J)]; \
    int v = e / 3; int k = e - 3 * v; \
    float ch = chn[v * BATCH + b]; \
    float p0 = (float)c2v_prev[(3 * v + 0) * BATCH + b]; \
    float p1 = (float)c2v_prev[(3 * v + 1) * BATCH + b]; \
    float p2 = (float)c2v_prev[(3 * v + 2) * BATCH + b]; \
    float vold = (float)v2c[(base + (J)) * BATCH + b]; \
    float tot = ch + p0 + p1 + p2; \
    if (iter > 0 && k == 0) \
        __builtin_nontemporal_store(tot, &out_t[v * BATCH + b]); \
    float cprev = (k == 0) ? p0 : ((k == 1) ? p1 : p2); \
    float vnew = g * (tot - cprev) + om * vold; \
    v2c[(base + (J)) * BATCH + b] = (_Float16)vnew; \
    float x = fminf(fmaxf(vnew, -15.0f), 15.0f); \
    la[J] = log_tanh_half(fabsf(x)); \
    sum_log += la[J]; \
    mask |= (unsigned)(x < 0.0f ? 1u : 0u) << (J); }

    switch (deg) {
      case 32: P1(31) [[fallthrough]]; case 31: P1(30) [[fallthrough]];
      case 30: P1(29) [[fallthrough]]; case 29: P1(28) [[fallthrough]];
      case 28: P1(27) [[fallthrough]]; case 27: P1(26) [[fallthrough]];
      case 26: P1(25) [[fallthrough]]; case 25: P1(24) [[fallthrough]];
      case 24: P1(23) [[fallthrough]]; case 23: P1(22) [[fallthrough]];
      case 22: P1(21) [[fallthrough]]; case 21: P1(20) [[fallthrough]];
      case 20: P1(19) [[fallthrough]]; case 19: P1(18) [[fallthrough]];
      case 18: P1(17) [[fallthrough]]; case 17: P1(16) [[fallthrough]];
      case 16: P1(15) [[fallthrough]]; case 15: P1(14) [[fallthrough]];
      case 14: P1(13) [[fallthrough]]; case 13: P1(12) [[fallthrough]];
      case 12: P1(11) [[fallthrough]]; case 11: P1(10) [[fallthrough]];
      case 10: P1(9)  [[fallthrough]]; case 9:  P1(8)  [[fallthrough]];
      case 8:  P1(7)  [[fallthrough]]; case 7:  P1(6)  [[fallthrough]];
      case 6:  P1(5)  [[fallthrough]]; case 5:  P1(4)  [[fallthrough]];
      case 4:  P1(3)  [[fallthrough]]; case 3:  P1(2)  [[fallthrough]];
      case 2:  P1(1)  [[fallthrough]]; case 1:  P1(0)  [[fallthrough]];
      default: break;
    }
#undef P1

    int totneg = __popc(mask);

#define P2(J) { \
    int e = ell[c * ELLW + (J)]; \
    float m = back_transform(sum_log - la[J]); \
    int par = (totneg - (int)((mask >> (J)) & 1u)) & 1; \
    c2v_next[e * BATCH + b] = (_Float16)(par ? -m : m); }

    switch (deg) {
      case 32: P2(31) [[fallthrough]]; case 31: P2(30) [[fallthrough]];
      case 30: P2(29) [[fallthrough]]; case 29: P2(28) [[fallthrough]];
      case 28: P2(27) [[fallthrough]]; case 27: P2(26) [[fallthrough]];
      case 26: P2(25) [[fallthrough]]; case 25: P2(24) [[fallthrough]];
      case 24: P2(23) [[fallthrough]]; case 23: P2(22) [[fallthrough]];
      case 22: P2(21) [[fallthrough]]; case 21: P2(20) [[fallthrough]];
      case 20: P2(19) [[fallthrough]]; case 19: P2(18) [[fallthrough]];
      case 18: P2(17) [[fallthrough]]; case 17: P2(16) [[fallthrough]];
      case 16: P2(15) [[fallthrough]]; case 15: P2(14) [[fallthrough]];
      case 14: P2(13) [[fallthrough]]; case 13: P2(12) [[fallthrough]];
      case 12: P2(11) [[fallthrough]]; case 11: P2(10) [[fallthrough]];
      case 10: P2(9)  [[fallthrough]]; case 9:  P2(8)  [[fallthrough]];
      case 8:  P2(7)  [[fallthrough]]; case 7:  P2(6)  [[fallthrough]];
      case 6:  P2(5)  [[fallthrough]]; case 5:  P2(4)  [[fallthrough]];
      case 4:  P2(3)  [[fallthrough]]; case 3:  P2(2)  [[fallthrough]];
      case 2:  P2(1)  [[fallthrough]]; case 1:  P2(0)  [[fallthrough]];
      default: break;
    }
#undef P2
}

// ---------------- Final posterior (out[T-1]) -------------------------------

__global__ __launch_bounds__(256) void k_out_final(const float* __restrict__ chn,
                                                   const _Float16* __restrict__ c2v,
                                                   float* __restrict__ out) {
    int gid = blockIdx.x * 256 + threadIdx.x;
    int v = gid >> 5;
    int q = gid & 31;
    const h4* rows = (const h4*)c2v;              // edge row e -> e*32 + q
    h4 c0 = rows[(3 * v + 0) * 32 + q];
    h4 c1 = rows[(3 * v + 1) * 32 + q];
    h4 c2 = rows[(3 * v + 2) * 32 + q];
    v4f ch = ((const v4f*)chn)[v * 32 + q];
    v4f tot;
    tot.x = ch.x + (float)c0.x + (float)c1.x + (float)c2.x;
    tot.y = ch.y + (float)c0.y + (float)c1.y + (float)c2.y;
    tot.z = ch.z + (float)c0.z + (float)c1.z + (float)c2.z;
    tot.w = ch.w + (float)c0.w + (float)c1.w + (float)c2.w;
    v4f* o = (v4f*)(out + (size_t)(T_ITERS - 1) * (N_VAR * BATCH));
    __builtin_nontemporal_store(tot, &o[v * 32 + q]);
}

// ---------------- Launch ---------------------------------------------------

extern "C" void kernel_launch(void* const* d_in, const int* in_sizes, int n_in,
                              void* d_out, int out_size, void* d_ws, size_t ws_size,
                              hipStream_t stream) {
    const float* chn         = (const float*)d_in[0];
    const float* gamma_logit = (const float*)d_in[1];
    // d_in[2] = edge_var (deterministic: e/3) — not needed
    const int* edge_chk      = (const int*)d_in[3];
    float* out = (float*)d_out;

    const size_t MSG = (size_t)N_EDGE * BATCH;     // halfs per message array
    _Float16* c2v_a = (_Float16*)d_ws;
    _Float16* c2v_b = c2v_a + MSG;
    _Float16* v2c   = c2v_b + MSG;
    int* ell     = (int*)(v2c + MSG);
    int* deg_arr = ell + (size_t)N_CHK * ELLW;
    int* ptr     = deg_arr + N_CHK;

    // zero the three fp16 message arrays (contiguous) + ell + deg
    (void)hipMemsetAsync(c2v_a, 0, 3 * MSG * sizeof(_Float16), stream);
    (void)hipMemsetAsync(ell, 0, sizeof(int) * ((size_t)N_CHK * ELLW + N_CHK), stream);

    k_ell_scatter<<<(N_EDGE + 255) / 256, 256, 0, stream>>>(edge_chk, deg_arr, ell);
    k_scan<<<1, 1024, 0, stream>>>(deg_arr, ptr);

    for (int t = 0; t < T_ITERS; ++t) {
        const _Float16* prev = (t & 1) ? c2v_b : c2v_a;
        _Float16*       next = (t & 1) ? c2v_a : c2v_b;
        k_fused<<<N_CHK / 2, 256, 0, stream>>>(chn, gamma_logit, prev, next, v2c,
                                               deg_arr, ell, ptr, out, t);
    }
    // t=29 (odd) wrote c2v_a
    k_out_final<<<(N_VAR * BATCH / 4) / 256, 256, 0, stream>>>(chn, c2v_a, out);
}

// Round 6
// 694.398 us; speedup vs baseline: 1.0411x; 1.0411x over previous
//
#include <hip/hip_runtime.h>
#include <math.h>

#define N_VAR 8192
#define N_CHK 4096
#define DV 3
#define N_EDGE (N_VAR * DV)
#define BATCH 128
#define T_ITERS 30
#define ELLW 24
#define PREF 12

#define LOG2E 1.44269504088896340736f
#define LN2   0.69314718055994530942f

typedef float v4f __attribute__((ext_vector_type(4)));

// tanh(x/2), sign preserved, |t| floored at 1e-7 (matches reference clamp);
// x pre-clipped to [-15,15]
__device__ __forceinline__ float tanh_half(float x) {
    float ex = __builtin_amdgcn_exp2f(x * LOG2E);              // e^x
    float t = 1.0f - 2.0f * __builtin_amdgcn_rcpf(ex + 1.0f);
    float s = (x < 0.0f) ? -1.0f : 1.0f;
    return s * fmaxf(fabsf(t), 1e-7f);
}

// 2*atanh(clip(p)) — reference's clip(-1+eps, 1-eps) then 2 atanh
__device__ __forceinline__ float atanh2(float p) {
    const float lim = 1.0f - 1e-7f;
    p = fminf(fmaxf(p, -lim), lim);
    return (__builtin_amdgcn_logf(1.0f + p) -
            __builtin_amdgcn_logf(1.0f - p)) * LN2;
}

// ---------------- graph build (once per launch) ----------------------------

__global__ void k_ell_scatter(const int* __restrict__ edge_chk,
                              int* __restrict__ deg_arr, int* __restrict__ var_ell) {
    int e = blockIdx.x * blockDim.x + threadIdx.x;
    if (e < N_EDGE) {
        int c = edge_chk[e];
        int pos = atomicAdd(&deg_arr[c], 1);
        if (pos < ELLW) var_ell[c * ELLW + pos] = e / 3;   // store variable id
    }
}

// exclusive prefix over 4096 degs -> ptr (compact slot offsets)
__global__ __launch_bounds__(1024) void k_scan(const int* __restrict__ counts,
                                               int* __restrict__ ptr) {
    __shared__ int bufA[1024];
    __shared__ int bufB[1024];
    int t = threadIdx.x;
    int c0 = counts[4 * t + 0];
    int c1 = counts[4 * t + 1];
    int c2 = counts[4 * t + 2];
    int c3 = counts[4 * t + 3];
    int s = c0 + c1 + c2 + c3;
    bufA[t] = s;
    __syncthreads();
    int* src = bufA;
    int* dst = bufB;
    for (int off = 1; off < 1024; off *= 2) {
        int v = src[t];
        if (t >= off) v += src[t - off];
        dst[t] = v;
        __syncthreads();
        int* tmp = src; src = dst; dst = tmp;
    }
    int incl = src[t];
    int excl = incl - s;
    ptr[4 * t + 0] = excl;
    ptr[4 * t + 1] = excl + c0;
    ptr[4 * t + 2] = excl + c0 + c1;
    ptr[4 * t + 3] = excl + c0 + c1 + c2;
    if (t == 1023) ptr[N_CHK] = incl;
}

// ---------------- prefill: out[t][v][b] = chn[v][b] for all t --------------

__global__ __launch_bounds__(256) void k_prefill(const float* __restrict__ chn,
                                                 float* __restrict__ out) {
    int gid = blockIdx.x * 256 + threadIdx.x;          // 0 .. 262143
    v4f c = ((const v4f*)chn)[gid];
#pragma unroll
    for (int tt = 0; tt < T_ITERS; ++tt) {
        v4f* o = (v4f*)(out + (size_t)tt * (N_VAR * BATCH));
        __builtin_nontemporal_store(c, &o[gid]);
    }
}

// ---------------- one BP iteration: block (128 thr) per check --------------
// post_prev = out[t-1] (or chn at t=0); out_t pre-filled with chn.
// V2C/C2V in compact per-check slots (fp16, single-buffered: owner-only).

__global__ __launch_bounds__(128) void k_iter(
        const float* __restrict__ post_prev,
        float* __restrict__ out_t,
        const float* __restrict__ gamma_logit,
        _Float16* __restrict__ c2v,
        _Float16* __restrict__ v2c,
        const int* __restrict__ var_ell,
        const int* __restrict__ deg_arr,
        const int* __restrict__ ptr) {
    int c = blockIdx.x;
    int b = threadIdx.x;
    int deg = deg_arr[c];
    if (deg > ELLW) deg = ELLW;
    if (deg == 0) return;
    int base = ptr[c];
    float g = 1.0f / (1.0f + __builtin_amdgcn_exp2f(-gamma_logit[0] * LOG2E));
    float om = 1.0f - g;

    // variable ids: block-uniform -> scalar loads
    int vid[ELLW];
#pragma unroll
    for (int j = 0; j < ELLW; ++j) vid[j] = var_ell[c * ELLW + j];

    // front-load first PREF slots unconditionally (independent, in flight)
    float pre_post[PREF], pre_cp[PREF], pre_vo[PREF];
#pragma unroll
    for (int j = 0; j < PREF; ++j) {
        int s = base + j;
        s = (s < N_EDGE) ? s : (N_EDGE - 1);           // clamp past-the-end
        pre_post[j] = post_prev[vid[j] * BATCH + b];
        pre_cp[j] = (float)c2v[s * BATCH + b];
        pre_vo[j] = (float)v2c[s * BATCH + b];
    }

    float t[ELLW];
#pragma unroll
    for (int j = 0; j < ELLW; ++j) {
        if (j < deg) {                                  // wave-uniform branch
            float postv, cpv, vov;
            if (j < PREF) {
                postv = pre_post[j]; cpv = pre_cp[j]; vov = pre_vo[j];
            } else {
                int s = base + j;
                postv = post_prev[vid[j] * BATCH + b];
                cpv = (float)c2v[s * BATCH + b];
                vov = (float)v2c[s * BATCH + b];
            }
            float vn = g * (postv - cpv) + om * vov;
            v2c[(base + j) * BATCH + b] = (_Float16)vn;
            float x = fminf(fmaxf(vn, -15.0f), 15.0f);
            t[j] = tanh_half(x);
        }
    }

    // suffix products: ext[j] = prod_{k>j} t[k]
    float ext[ELLW];
    float run = 1.0f;
#pragma unroll
    for (int j = ELLW - 1; j >= 0; --j) {
        if (j < deg) { ext[j] = run; run *= t[j]; }
    }
    // prefix sweep + emit
    float pfx = 1.0f;
#pragma unroll
    for (int j = 0; j < ELLW; ++j) {
        if (j < deg) {
            float p = pfx * ext[j];                     // prod of others
            pfx *= t[j];
            float m = atanh2(p);
            c2v[(base + j) * BATCH + b] = (_Float16)m;
            unsafeAtomicAdd(&out_t[vid[j] * BATCH + b], m);
        }
    }
}

// ---------------- Launch ---------------------------------------------------

extern "C" void kernel_launch(void* const* d_in, const int* in_sizes, int n_in,
                              void* d_out, int out_size, void* d_ws, size_t ws_size,
                              hipStream_t stream) {
    const float* chn         = (const float*)d_in[0];
    const float* gamma_logit = (const float*)d_in[1];
    // d_in[2] = edge_var (deterministic: e/3) — not needed
    const int* edge_chk      = (const int*)d_in[3];
    float* out = (float*)d_out;

    const size_t MSG = (size_t)N_EDGE * BATCH;         // halfs per msg array
    _Float16* c2v = (_Float16*)d_ws;
    _Float16* v2c = c2v + MSG;
    int* var_ell = (int*)(v2c + MSG);
    int* deg_arr = var_ell + (size_t)N_CHK * ELLW;
    int* ptr     = deg_arr + N_CHK;

    (void)hipMemsetAsync(c2v, 0, 2 * MSG * sizeof(_Float16), stream);
    (void)hipMemsetAsync(var_ell, 0,
                         sizeof(int) * ((size_t)N_CHK * ELLW + N_CHK), stream);

    k_ell_scatter<<<(N_EDGE + 255) / 256, 256, 0, stream>>>(edge_chk, deg_arr,
                                                            var_ell);
    k_scan<<<1, 1024, 0, stream>>>(deg_arr, ptr);
    k_prefill<<<(N_VAR * BATCH / 4) / 256, 256, 0, stream>>>(chn, out);

    const size_t SLICE = (size_t)N_VAR * BATCH;
    for (int t = 0; t < T_ITERS; ++t) {
        const float* post_prev = (t == 0) ? chn : (out + (size_t)(t - 1) * SLICE);
        float* out_t = out + (size_t)t * SLICE;
        k_iter<<<N_CHK, 128, 0, stream>>>(post_prev, out_t, gamma_logit,
                                          c2v, v2c, var_ell, deg_arr, ptr);
    }
}